// Round 5
// baseline (175.856 us; speedup 1.0000x reference)
//
#include <hip/hip_runtime.h>
#include <hip/hip_bf16.h>
#include <math.h>

// Hyperbolic (Poincare-ball) pairwise distance:
//   out[b,h,n,m] = arccosh(1 + 2*c*||q_n-k_m||^2 / ((1-c||q_n||^2)(1-c||k_m||^2)))
// c = 1.0. Shapes: q,k f32[4,8,2048,64] -> out f32[4,8,2048,2048].
//
// R1 -> R3: VALU-bound fix (recip denominators, HW sqrt/log2, swapped MFMA
//   operands -> float4 stores). 424 -> 160 us.
// R4: (256,4) occupancy bump REGRESSED (175 us) -> reverted.
// R5: drop __builtin_nontemporal_store. Each wave store covers only 64 B per
//   output row (4 lanes x 16 B); nt (evict-first) pushed half-dirty lines out
//   before the adjacent j-iteration's 64 B could merge -> ~2x write cost.
//   Model: (537*2+75) MB / 6.7 TB/s ~= 172 us == observed. Plain stores let
//   L2 write-combine to full 128 B lines; output streams once.

typedef __bf16 bf16x8 __attribute__((ext_vector_type(8)));
typedef float f32x4 __attribute__((ext_vector_type(4)));

#define NSEQ 2048
#define DDIM 64
#define TILE 128
#define LDSW 72   // ushorts; 144 B row stride, keeps 16 B alignment for b128

static __device__ __forceinline__ unsigned short f32_to_bf16_rne(float f) {
    unsigned int u = __builtin_bit_cast(unsigned int, f);
    u += 0x7fffu + ((u >> 16) & 1u);   // round-to-nearest-even
    return (unsigned short)(u >> 16);
}

__global__ __launch_bounds__(256, 2)
void hyp_dist_tile_kernel(const float* __restrict__ qg,
                          const float* __restrict__ kg,
                          float* __restrict__ outg)
{
    __shared__ __align__(16) unsigned short Qs[TILE * LDSW];
    __shared__ __align__(16) unsigned short Ks[TILE * LDSW];
    __shared__ __align__(16) float qn[TILE];   // ||q||^2
    __shared__ __align__(16) float kn[TILE];   // ||k||^2
    __shared__ __align__(16) float qi2[TILE];  // 2/(1-||q||^2)
    __shared__ __align__(16) float ki[TILE];   // 1/(1-||k||^2)

    const int bid  = blockIdx.x;
    const int bh   = bid >> 8;    // 0..31  (B*H)
    const int tile = bid & 255;   // 16x16 tiles of 128x128
    const int tr   = tile >> 4;
    const int tc   = tile & 15;

    const int t    = threadIdx.x;  // 256 threads = 4 waves
    const int row  = t >> 1;       // 0..127
    const int half = t & 1;        // each thread: half a row (32 f32)

    // ---- stage Q tile (f32 -> bf16 LDS) + row norms / recips in f32 ----
    {
        const float* src = qg + (((size_t)bh * NSEQ) + (size_t)(tr * TILE + row)) * DDIM
                              + half * 32;
        float partial = 0.f;
        #pragma unroll
        for (int i = 0; i < 8; ++i) {
            float4 v = reinterpret_cast<const float4*>(src)[i];
            partial += v.x * v.x + v.y * v.y + v.z * v.z + v.w * v.w;
            ushort4 b;
            b.x = f32_to_bf16_rne(v.x);
            b.y = f32_to_bf16_rne(v.y);
            b.z = f32_to_bf16_rne(v.z);
            b.w = f32_to_bf16_rne(v.w);
            *reinterpret_cast<ushort4*>(&Qs[row * LDSW + half * 32 + i * 4]) = b;
        }
        partial += __shfl_xor(partial, 1);
        if (half == 0) {
            qn[row]  = partial;
            // per-factor clamp 1e-3 -> product >= 1e-6 (reference clamp level)
            qi2[row] = 2.f * __builtin_amdgcn_rcpf(fmaxf(1.f - partial, 1e-3f));
        }
    }
    // ---- stage K tile ----
    {
        const float* src = kg + (((size_t)bh * NSEQ) + (size_t)(tc * TILE + row)) * DDIM
                              + half * 32;
        float partial = 0.f;
        #pragma unroll
        for (int i = 0; i < 8; ++i) {
            float4 v = reinterpret_cast<const float4*>(src)[i];
            partial += v.x * v.x + v.y * v.y + v.z * v.z + v.w * v.w;
            ushort4 b;
            b.x = f32_to_bf16_rne(v.x);
            b.y = f32_to_bf16_rne(v.y);
            b.z = f32_to_bf16_rne(v.z);
            b.w = f32_to_bf16_rne(v.w);
            *reinterpret_cast<ushort4*>(&Ks[row * LDSW + half * 32 + i * 4]) = b;
        }
        partial += __shfl_xor(partial, 1);
        if (half == 0) {
            kn[row] = partial;
            ki[row] = __builtin_amdgcn_rcpf(fmaxf(1.f - partial, 1e-3f));
        }
    }

    __syncthreads();

    // ---- MFMA: each wave computes a 64x64 sub-tile (4x4 frags of 16x16) ----
    const int wid   = t >> 6;
    const int lane  = t & 63;
    const int waveR = (wid >> 1) * 64;  // 2x2 wave grid
    const int waveC = (wid & 1) * 64;
    const int lr    = lane & 15;
    const int lg    = lane >> 4;

    f32x4 acc[4][4];
    #pragma unroll
    for (int i = 0; i < 4; ++i)
        #pragma unroll
        for (int j = 0; j < 4; ++j)
            acc[i][j] = (f32x4){0.f, 0.f, 0.f, 0.f};

    // acc[i][j] = mfma(K_frag[j], Q_frag[i]): D layout is q_idx = lane&15,
    // k_idx = (lane>>4)*4 + reg -> 4 regs = 4 consecutive output columns.
    #pragma unroll
    for (int ks = 0; ks < 2; ++ks) {
        bf16x8 af[4], bfr[4];
        #pragma unroll
        for (int f = 0; f < 4; ++f) {
            af[f]  = *reinterpret_cast<const bf16x8*>(
                         &Qs[(waveR + f * 16 + lr) * LDSW + ks * 32 + lg * 8]);
            bfr[f] = *reinterpret_cast<const bf16x8*>(
                         &Ks[(waveC + f * 16 + lr) * LDSW + ks * 32 + lg * 8]);
        }
        #pragma unroll
        for (int i = 0; i < 4; ++i)
            #pragma unroll
            for (int j = 0; j < 4; ++j)
                acc[i][j] = __builtin_amdgcn_mfma_f32_16x16x32_bf16(
                                bfr[j], af[i], acc[i][j], 0, 0, 0);
    }

    // ---- epilogue: q_row = lane&15, k_col = (lane>>4)*4 + reg ----
    const size_t out_bh = (size_t)bh * NSEQ * NSEQ;
    const int    colb   = tc * TILE + waveC + lg * 4;   // thread's k-col base
    #pragma unroll
    for (int i = 0; i < 4; ++i) {
        const int   qrow = waveR + i * 16 + lr;
        const float qv   = qn[qrow];
        const float q2   = qi2[qrow];   // 2/(1-|q|^2)
        float* rowp = outg + out_bh + (size_t)(tr * TILE + qrow) * NSEQ + colb;
        #pragma unroll
        for (int j = 0; j < 4; ++j) {
            const int kbase = waveC + j * 16 + lg * 4;
            const f32x4 kv  = *reinterpret_cast<const f32x4*>(&kn[kbase]);
            const f32x4 kiv = *reinterpret_cast<const f32x4*>(&ki[kbase]);
            f32x4 res;
            #pragma unroll
            for (int r = 0; r < 4; ++r) {
                const float dot  = acc[i][j][r];
                const float diff = fmaxf(fmaf(-2.f, dot, qv + kv[r]), 0.f); // ||q-k||^2
                const float tt   = diff * (q2 * kiv[r]);                    // cosh_arg-1
                const float p    = fmaf(tt, tt, 2.f * tt);                  // tt(tt+2)
                const float sq   = __builtin_amdgcn_sqrtf(p);
                const float x    = (1.f + tt) + sq;                         // >= 1
                const float l2   = __builtin_amdgcn_logf(x);                // log2
                res[r] = l2 * 0.69314718055994531f;                         // -> ln
            }
            *reinterpret_cast<f32x4*>(rowp + j * 16) = res;  // plain store: L2 merges lines
        }
    }
}

extern "C" void kernel_launch(void* const* d_in, const int* in_sizes, int n_in,
                              void* d_out, int out_size, void* d_ws, size_t ws_size,
                              hipStream_t stream) {
    const float* q = (const float*)d_in[0];
    const float* k = (const float*)d_in[1];
    float* out = (float*)d_out;
    // 32 (b,h) * 16 * 16 tiles of 128x128
    hyp_dist_tile_kernel<<<dim3(32 * 16 * 16), dim3(256), 0, stream>>>(q, k, out);
}

// Round 6
// 115.488 us; speedup vs baseline: 1.5227x; 1.5227x over previous
//
#include <hip/hip_runtime.h>
#include <hip/hip_bf16.h>
#include <math.h>

// Hyperbolic (Poincare-ball) pairwise distance:
//   out[b,h,n,m] = arccosh(1 + 2*c*||q_n-k_m||^2 / ((1-c||q_n||^2)(1-c||k_m||^2)))
// c = 1.0. Shapes: q,k f32[4,8,2048,64] -> out f32[4,8,2048,2048].
//
// R1 -> R3: VALU fixes (recip LDS, HW sqrt/log2, swapped MFMA operands,
//   f32x4 nt stores). 424 -> 160 us.
// R4: (256,4) occupancy bump regressed (175) -> keep (256,2).
// R5: plain stores regressed (176) -> keep __builtin_nontemporal_store.
// R6: store-pattern restructure. Old epilogue: each wave store = 16 rows x
//   64 B segments (half-lines scattered over 128 KB). Memset reference hits
//   6.6 TB/s with full-line streaming; we were at ~4.1 TB/s effective.
//   Now: epilogue results bounce through LDS ([64][132] f32, reusing Qs/Ks
//   space) so each wave store = 2 rows x 512 B contiguous (full 128 B
//   lines, 1024 B/instr). Wave->frag mapping: acc[2][8] = 2 x 16-row bands
//   x 128 cols per wave so all 4 waves produce AND stream both chunks.

typedef __bf16 bf16x8 __attribute__((ext_vector_type(8)));
typedef float f32x4 __attribute__((ext_vector_type(4)));

#define NSEQ 2048
#define DDIM 64
#define TILE 128
#define LDSW 72    // ushorts; 144 B row stride
#define LOUTW 132  // f32; 528 B row stride -> 2-way LDS conflicts (free)

static __device__ __forceinline__ unsigned short f32_to_bf16_rne(float f) {
    unsigned int u = __builtin_bit_cast(unsigned int, f);
    u += 0x7fffu + ((u >> 16) & 1u);   // round-to-nearest-even
    return (unsigned short)(u >> 16);
}

__global__ __launch_bounds__(256, 2)
void hyp_dist_tile_kernel(const float* __restrict__ qg,
                          const float* __restrict__ kg,
                          float* __restrict__ outg)
{
    // Qs+Ks (36864 B) aliased with Lout (64*132*4 = 33792 B): MFMA is done
    // with Qs/Ks before the first Lout write (barrier-protected).
    __shared__ __align__(16) unsigned char lds_raw[2 * TILE * LDSW * 2];
    __shared__ __align__(16) float qn[TILE];   // ||q||^2
    __shared__ __align__(16) float kn[TILE];   // ||k||^2
    __shared__ __align__(16) float qi2[TILE];  // 2/(1-||q||^2)
    __shared__ __align__(16) float ki[TILE];   // 1/(1-||k||^2)

    unsigned short* Qs = reinterpret_cast<unsigned short*>(lds_raw);
    unsigned short* Ks = Qs + TILE * LDSW;
    float*          Lout = reinterpret_cast<float*>(lds_raw);

    const int bid  = blockIdx.x;
    const int bh   = bid >> 8;    // 0..31  (B*H)
    const int tile = bid & 255;   // 16x16 tiles of 128x128
    const int tr   = tile >> 4;
    const int tc   = tile & 15;

    const int t    = threadIdx.x;  // 256 threads = 4 waves
    const int row  = t >> 1;       // 0..127
    const int half = t & 1;        // each thread: half a row (32 f32)

    // ---- stage Q tile (f32 -> bf16 LDS) + row norms / recips in f32 ----
    {
        const float* src = qg + (((size_t)bh * NSEQ) + (size_t)(tr * TILE + row)) * DDIM
                              + half * 32;
        float partial = 0.f;
        #pragma unroll
        for (int i = 0; i < 8; ++i) {
            float4 v = reinterpret_cast<const float4*>(src)[i];
            partial += v.x * v.x + v.y * v.y + v.z * v.z + v.w * v.w;
            ushort4 b;
            b.x = f32_to_bf16_rne(v.x);
            b.y = f32_to_bf16_rne(v.y);
            b.z = f32_to_bf16_rne(v.z);
            b.w = f32_to_bf16_rne(v.w);
            *reinterpret_cast<ushort4*>(&Qs[row * LDSW + half * 32 + i * 4]) = b;
        }
        partial += __shfl_xor(partial, 1);
        if (half == 0) {
            qn[row]  = partial;
            // per-factor clamp 1e-3 -> product >= 1e-6 (reference clamp level)
            qi2[row] = 2.f * __builtin_amdgcn_rcpf(fmaxf(1.f - partial, 1e-3f));
        }
    }
    // ---- stage K tile ----
    {
        const float* src = kg + (((size_t)bh * NSEQ) + (size_t)(tc * TILE + row)) * DDIM
                              + half * 32;
        float partial = 0.f;
        #pragma unroll
        for (int i = 0; i < 8; ++i) {
            float4 v = reinterpret_cast<const float4*>(src)[i];
            partial += v.x * v.x + v.y * v.y + v.z * v.z + v.w * v.w;
            ushort4 b;
            b.x = f32_to_bf16_rne(v.x);
            b.y = f32_to_bf16_rne(v.y);
            b.z = f32_to_bf16_rne(v.z);
            b.w = f32_to_bf16_rne(v.w);
            *reinterpret_cast<ushort4*>(&Ks[row * LDSW + half * 32 + i * 4]) = b;
        }
        partial += __shfl_xor(partial, 1);
        if (half == 0) {
            kn[row] = partial;
            ki[row] = __builtin_amdgcn_rcpf(fmaxf(1.f - partial, 1e-3f));
        }
    }

    __syncthreads();

    // ---- MFMA: wave w owns rows {w*16..w*16+15} and {64+w*16..}, all 128 cols
    const int wid   = t >> 6;
    const int lane  = t & 63;
    const int lr    = lane & 15;
    const int lg    = lane >> 4;

    f32x4 acc[2][8];
    #pragma unroll
    for (int c = 0; c < 2; ++c)
        #pragma unroll
        for (int j = 0; j < 8; ++j)
            acc[c][j] = (f32x4){0.f, 0.f, 0.f, 0.f};

    // acc[c][j] = mfma(K_frag[j], Q_frag[c]): D layout q_idx = lane&15,
    // k_idx = (lane>>4)*4 + reg -> 4 regs = 4 consecutive output columns.
    #pragma unroll
    for (int ks = 0; ks < 2; ++ks) {
        bf16x8 af[2], bfr[8];
        #pragma unroll
        for (int c = 0; c < 2; ++c)
            af[c] = *reinterpret_cast<const bf16x8*>(
                        &Qs[(c * 64 + wid * 16 + lr) * LDSW + ks * 32 + lg * 8]);
        #pragma unroll
        for (int j = 0; j < 8; ++j)
            bfr[j] = *reinterpret_cast<const bf16x8*>(
                        &Ks[(j * 16 + lr) * LDSW + ks * 32 + lg * 8]);
        #pragma unroll
        for (int c = 0; c < 2; ++c)
            #pragma unroll
            for (int j = 0; j < 8; ++j)
                acc[c][j] = __builtin_amdgcn_mfma_f32_16x16x32_bf16(
                                bfr[j], af[c], acc[c][j], 0, 0, 0);
    }

    // ---- epilogue: two 64-row chunks bounced through LDS for full-line
    //      contiguous streaming stores (2 rows x 512 B per wave instr). ----
    const size_t out_bh = (size_t)bh * NSEQ * NSEQ;
    const int    l5  = lane >> 5;      // 0..1
    const int    c32 = lane & 31;      // 0..31

    #pragma unroll
    for (int c = 0; c < 2; ++c) {
        // c==0: wait for all MFMA LDS reads before overwriting Qs/Ks with Lout.
        // c==1: wait for all chunk-0 streaming reads before overwriting Lout.
        __syncthreads();

        const int   trow = c * 64 + wid * 16 + lr;   // row within 128-tile
        const float qv   = qn[trow];
        const float q2   = qi2[trow];                // 2/(1-|q|^2)
        #pragma unroll
        for (int j = 0; j < 8; ++j) {
            const int kb = j * 16 + lg * 4;
            const f32x4 kv  = *reinterpret_cast<const f32x4*>(&kn[kb]);
            const f32x4 kiv = *reinterpret_cast<const f32x4*>(&ki[kb]);
            f32x4 res;
            #pragma unroll
            for (int r = 0; r < 4; ++r) {
                const float dot  = acc[c][j][r];
                const float diff = fmaxf(fmaf(-2.f, dot, qv + kv[r]), 0.f); // ||q-k||^2
                const float tt   = diff * (q2 * kiv[r]);                    // cosh_arg-1
                const float p    = fmaf(tt, tt, 2.f * tt);                  // tt(tt+2)
                const float sq   = __builtin_amdgcn_sqrtf(p);
                const float x    = (1.f + tt) + sq;                         // >= 1
                const float l2   = __builtin_amdgcn_logf(x);                // log2
                res[r] = l2 * 0.69314718055994531f;                         // -> ln
            }
            *reinterpret_cast<f32x4*>(&Lout[(wid * 16 + lr) * LOUTW + kb]) = res;
        }

        __syncthreads();

        // stream chunk: wave w -> chunk rows w*16..w*16+15; per instr 2 full rows.
        #pragma unroll
        for (int m = 0; m < 8; ++m) {
            const int crow = wid * 16 + m * 2 + l5;
            const f32x4 v  = *reinterpret_cast<const f32x4*>(&Lout[crow * LOUTW + c32 * 4]);
            float* gp = outg + out_bh
                      + (size_t)(tr * TILE + c * 64 + crow) * NSEQ
                      + (size_t)(tc * TILE + c32 * 4);
            __builtin_nontemporal_store(v, reinterpret_cast<f32x4*>(gp));
        }
    }
}

extern "C" void kernel_launch(void* const* d_in, const int* in_sizes, int n_in,
                              void* d_out, int out_size, void* d_ws, size_t ws_size,
                              hipStream_t stream) {
    const float* q = (const float*)d_in[0];
    const float* k = (const float*)d_in[1];
    float* out = (float*)d_out;
    // 32 (b,h) * 16 * 16 tiles of 128x128
    hyp_dist_tile_kernel<<<dim3(32 * 16 * 16), dim3(256), 0, stream>>>(q, k, out);
}

// Round 7
// 115.376 us; speedup vs baseline: 1.5242x; 1.0010x over previous
//
#include <hip/hip_runtime.h>
#include <hip/hip_bf16.h>
#include <math.h>

// Hyperbolic (Poincare-ball) pairwise distance:
//   out[b,h,n,m] = arccosh(1 + 2*c*||q_n-k_m||^2 / ((1-c||q_n||^2)(1-c||k_m||^2)))
// c = 1.0. Shapes: q,k f32[4,8,2048,64] -> out f32[4,8,2048,2048].
//
// R1 -> R3: VALU fixes (recip LDS, HW sqrt/log2, swapped MFMA operands,
//   f32x4 nt stores). 424 -> 160 us.
// R4: (256,4) occupancy bump regressed -> keep (256,2).
// R5: plain stores regressed -> keep nontemporal.
// R6: LDS-bounced epilogue -> full-line 1024 B/instr streaming stores.
//   160 -> 115.5 us. Cycle model: stores 80 + fetch 11 + epilogue 22 + misc
//   ~= 115 SERIALIZED -- matches exactly.
// R7: overlap store drain with compute. __syncthreads() emits
//   s_waitcnt vmcnt(0) before s_barrier, so each chunk's nt stores fully
//   drained to HBM before the next chunk's epilogue started. The inter-chunk
//   barriers only protect LDS reuse -> replace with lgkm-only barrier
//   (asm s_waitcnt lgkmcnt(0) + raw s_barrier). Stores stay in flight
//   across the barrier; epilogue VALU (~22 us) hides under the drain.

typedef __bf16 bf16x8 __attribute__((ext_vector_type(8)));
typedef float f32x4 __attribute__((ext_vector_type(4)));

#define NSEQ 2048
#define DDIM 64
#define TILE 128
#define LDSW 72    // ushorts; 144 B row stride
#define LOUTW 132  // f32; 528 B row stride -> 2-way LDS conflicts (free)

// Barrier that does NOT drain vmcnt (global stores keep flying).
// Each wave waits its own LDS ops, then syncs. Protects LDS reuse only.
#define LGKM_BARRIER()                                        \
    do {                                                      \
        asm volatile("s_waitcnt lgkmcnt(0)" ::: "memory");    \
        __builtin_amdgcn_s_barrier();                         \
    } while (0)

static __device__ __forceinline__ unsigned short f32_to_bf16_rne(float f) {
    unsigned int u = __builtin_bit_cast(unsigned int, f);
    u += 0x7fffu + ((u >> 16) & 1u);   // round-to-nearest-even
    return (unsigned short)(u >> 16);
}

__global__ __launch_bounds__(256, 2)
void hyp_dist_tile_kernel(const float* __restrict__ qg,
                          const float* __restrict__ kg,
                          float* __restrict__ outg)
{
    // Qs+Ks (36864 B) aliased with Lout (64*132*4 = 33792 B): MFMA is done
    // with Qs/Ks before the first Lout write (barrier-protected).
    __shared__ __align__(16) unsigned char lds_raw[2 * TILE * LDSW * 2];
    __shared__ __align__(16) float qn[TILE];   // ||q||^2
    __shared__ __align__(16) float kn[TILE];   // ||k||^2
    __shared__ __align__(16) float qi2[TILE];  // 2/(1-||q||^2)
    __shared__ __align__(16) float ki[TILE];   // 1/(1-||k||^2)

    unsigned short* Qs = reinterpret_cast<unsigned short*>(lds_raw);
    unsigned short* Ks = Qs + TILE * LDSW;
    float*          Lout = reinterpret_cast<float*>(lds_raw);

    const int bid  = blockIdx.x;
    const int bh   = bid >> 8;    // 0..31  (B*H)
    const int tile = bid & 255;   // 16x16 tiles of 128x128
    const int tr   = tile >> 4;
    const int tc   = tile & 15;

    const int t    = threadIdx.x;  // 256 threads = 4 waves
    const int row  = t >> 1;       // 0..127
    const int half = t & 1;        // each thread: half a row (32 f32)

    // ---- stage Q tile (f32 -> bf16 LDS) + row norms / recips in f32 ----
    {
        const float* src = qg + (((size_t)bh * NSEQ) + (size_t)(tr * TILE + row)) * DDIM
                              + half * 32;
        float partial = 0.f;
        #pragma unroll
        for (int i = 0; i < 8; ++i) {
            float4 v = reinterpret_cast<const float4*>(src)[i];
            partial += v.x * v.x + v.y * v.y + v.z * v.z + v.w * v.w;
            ushort4 b;
            b.x = f32_to_bf16_rne(v.x);
            b.y = f32_to_bf16_rne(v.y);
            b.z = f32_to_bf16_rne(v.z);
            b.w = f32_to_bf16_rne(v.w);
            *reinterpret_cast<ushort4*>(&Qs[row * LDSW + half * 32 + i * 4]) = b;
        }
        partial += __shfl_xor(partial, 1);
        if (half == 0) {
            qn[row]  = partial;
            // per-factor clamp 1e-3 -> product >= 1e-6 (reference clamp level)
            qi2[row] = 2.f * __builtin_amdgcn_rcpf(fmaxf(1.f - partial, 1e-3f));
        }
    }
    // ---- stage K tile ----
    {
        const float* src = kg + (((size_t)bh * NSEQ) + (size_t)(tc * TILE + row)) * DDIM
                              + half * 32;
        float partial = 0.f;
        #pragma unroll
        for (int i = 0; i < 8; ++i) {
            float4 v = reinterpret_cast<const float4*>(src)[i];
            partial += v.x * v.x + v.y * v.y + v.z * v.z + v.w * v.w;
            ushort4 b;
            b.x = f32_to_bf16_rne(v.x);
            b.y = f32_to_bf16_rne(v.y);
            b.z = f32_to_bf16_rne(v.z);
            b.w = f32_to_bf16_rne(v.w);
            *reinterpret_cast<ushort4*>(&Ks[row * LDSW + half * 32 + i * 4]) = b;
        }
        partial += __shfl_xor(partial, 1);
        if (half == 0) {
            kn[row] = partial;
            ki[row] = __builtin_amdgcn_rcpf(fmaxf(1.f - partial, 1e-3f));
        }
    }

    __syncthreads();

    // ---- MFMA: wave w owns rows {w*16..w*16+15} and {64+w*16..}, all 128 cols
    const int wid   = t >> 6;
    const int lane  = t & 63;
    const int lr    = lane & 15;
    const int lg    = lane >> 4;

    f32x4 acc[2][8];
    #pragma unroll
    for (int c = 0; c < 2; ++c)
        #pragma unroll
        for (int j = 0; j < 8; ++j)
            acc[c][j] = (f32x4){0.f, 0.f, 0.f, 0.f};

    // acc[c][j] = mfma(K_frag[j], Q_frag[c]): D layout q_idx = lane&15,
    // k_idx = (lane>>4)*4 + reg -> 4 regs = 4 consecutive output columns.
    #pragma unroll
    for (int ks = 0; ks < 2; ++ks) {
        bf16x8 af[2], bfr[8];
        #pragma unroll
        for (int c = 0; c < 2; ++c)
            af[c] = *reinterpret_cast<const bf16x8*>(
                        &Qs[(c * 64 + wid * 16 + lr) * LDSW + ks * 32 + lg * 8]);
        #pragma unroll
        for (int j = 0; j < 8; ++j)
            bfr[j] = *reinterpret_cast<const bf16x8*>(
                        &Ks[(j * 16 + lr) * LDSW + ks * 32 + lg * 8]);
        #pragma unroll
        for (int c = 0; c < 2; ++c)
            #pragma unroll
            for (int j = 0; j < 8; ++j)
                acc[c][j] = __builtin_amdgcn_mfma_f32_16x16x32_bf16(
                                bfr[j], af[c], acc[c][j], 0, 0, 0);
    }

    // ---- epilogue: two 64-row chunks bounced through LDS for full-line
    //      contiguous streaming stores (2 rows x 512 B per wave instr). ----
    const size_t out_bh = (size_t)bh * NSEQ * NSEQ;
    const int    l5  = lane >> 5;      // 0..1
    const int    c32 = lane & 31;      // 0..31

    #pragma unroll
    for (int c = 0; c < 2; ++c) {
        // c==0: all MFMA ds_reads done before overwriting Qs/Ks with Lout.
        // c==1: all chunk-0 streaming ds_reads done before overwriting Lout.
        // LDS-only hazard -> lgkm barrier; nt stores stay in flight.
        LGKM_BARRIER();

        const int   trow = c * 64 + wid * 16 + lr;   // row within 128-tile
        const float qv   = qn[trow];
        const float q2   = qi2[trow];                // 2/(1-|q|^2)
        #pragma unroll
        for (int j = 0; j < 8; ++j) {
            const int kb = j * 16 + lg * 4;
            const f32x4 kv  = *reinterpret_cast<const f32x4*>(&kn[kb]);
            const f32x4 kiv = *reinterpret_cast<const f32x4*>(&ki[kb]);
            f32x4 res;
            #pragma unroll
            for (int r = 0; r < 4; ++r) {
                const float dot  = acc[c][j][r];
                const float diff = fmaxf(fmaf(-2.f, dot, qv + kv[r]), 0.f); // ||q-k||^2
                const float tt   = diff * (q2 * kiv[r]);                    // cosh_arg-1
                const float p    = fmaf(tt, tt, 2.f * tt);                  // tt(tt+2)
                const float sq   = __builtin_amdgcn_sqrtf(p);
                const float x    = (1.f + tt) + sq;                         // >= 1
                const float l2   = __builtin_amdgcn_logf(x);                // log2
                res[r] = l2 * 0.69314718055994531f;                         // -> ln
            }
            *reinterpret_cast<f32x4*>(&Lout[(wid * 16 + lr) * LOUTW + kb]) = res;
        }

        // all ds_writes of this chunk visible before any wave streams it.
        LGKM_BARRIER();

        // stream chunk: wave w -> chunk rows w*16..w*16+15; per instr 2 full rows.
        #pragma unroll
        for (int m = 0; m < 8; ++m) {
            const int crow = wid * 16 + m * 2 + l5;
            const f32x4 v  = *reinterpret_cast<const f32x4*>(&Lout[crow * LOUTW + c32 * 4]);
            float* gp = outg + out_bh
                      + (size_t)(tr * TILE + c * 64 + crow) * NSEQ
                      + (size_t)(tc * TILE + c32 * 4);
            __builtin_nontemporal_store(v, reinterpret_cast<f32x4*>(gp));
        }
    }
}

extern "C" void kernel_launch(void* const* d_in, const int* in_sizes, int n_in,
                              void* d_out, int out_size, void* d_ws, size_t ws_size,
                              hipStream_t stream) {
    const float* q = (const float*)d_in[0];
    const float* k = (const float*)d_in[1];
    float* out = (float*)d_out;
    // 32 (b,h) * 16 * 16 tiles of 128x128
    hyp_dist_tile_kernel<<<dim3(32 * 16 * 16), dim3(256), 0, stream>>>(q, k, out);
}